// Round 10
// baseline (127.394 us; speedup 1.0000x reference)
//
#include <hip/hip_runtime.h>
#include <hip/hip_fp16.h>
#include <stdint.h>

// x[16384,2048] f32, w[2048,2048] f32, bias[2048] f32, scalar scales.
// M=16384, N=2048, K=2048. Output f16 values stored as f32.
#define MDIM 16384
#define NDIM 2048
#define KDIM 2048

typedef __attribute__((ext_vector_type(4))) float f32x4;
typedef __attribute__((ext_vector_type(4))) int   i32x4;
typedef __attribute__((ext_vector_type(8))) int   i32x8;

// ---------------------------------------------------------------------------
// Bit-exact f32 -> e4m3fn (OCP) RTNE after clip to +-448.
// ---------------------------------------------------------------------------
__device__ __forceinline__ unsigned f32_to_e4m3(float x) {
    float q = fminf(448.f, fmaxf(-448.f, x));
    unsigned ub = __float_as_uint(q);
    unsigned sgn = (ub >> 24) & 0x80u;
    float aq = fabsf(q);
    int E = (int)((__float_as_uint(aq) >> 23) & 0xff) - 127;
    if (E < -6) E = -6;
    float rq = __uint_as_float((unsigned)(130 - E) << 23);  // 2^(3-E), exact
    int m = (int)rintf(aq * rq);                            // RTNE, exact scale
    if (m == 16) { m = 8; E += 1; }
    unsigned bits;
    if (m < 8) bits = sgn | (unsigned)m;
    else       bits = sgn | ((unsigned)(E + 7) << 3) | (unsigned)(m - 8);
    return bits;
}

__device__ __forceinline__ void quant_span(const float* __restrict__ x,
                                           uint8_t* __restrict__ q, float sc,
                                           unsigned i0, unsigned stride,
                                           unsigned n16) {
    for (unsigned i = i0; i < n16; i += stride) {
        const float4* xp = (const float4*)(x + (size_t)i * 16);
        uint32_t w[4];
#pragma unroll
        for (int j = 0; j < 4; ++j) {
            float4 v = xp[j];
            w[j] = f32_to_e4m3(v.x / sc) | (f32_to_e4m3(v.y / sc) << 8) |
                   (f32_to_e4m3(v.z / sc) << 16) | (f32_to_e4m3(v.w / sc) << 24);
        }
        ((uint4*)q)[i] = make_uint4(w[0], w[1], w[2], w[3]);
    }
}

// Single dispatch: blocks [0,2048) quantize x, [2048,2304) quantize w.
__global__ void quant_both_kernel(const float* __restrict__ x,
                                  uint8_t* __restrict__ xq,
                                  const float* __restrict__ w,
                                  uint8_t* __restrict__ wq,
                                  const float* __restrict__ s_in,
                                  const float* __restrict__ s_w) {
    if (blockIdx.x < 2048) {
        unsigned i0 = blockIdx.x * 256 + threadIdx.x;
        quant_span(x, xq, s_in[0], i0, 2048 * 256,
                   (unsigned)((size_t)MDIM * KDIM / 16));
    } else {
        unsigned i0 = (blockIdx.x - 2048) * 256 + threadIdx.x;
        quant_span(w, wq, s_w[0], i0, 256 * 256,
                   (unsigned)((size_t)NDIM * KDIM / 16));
    }
}

// ---------------------------------------------------------------------------
// GEMM: C = Aq * Bq^T, fp8 e4m3, mfma_scale_f32_16x16x128_f8f6f4 (unit
// scales: exact, 2x fp8 rate, 32 contiguous K-bytes/lane; verified r4-r9).
//
// Round-10 GEOMETRY change (r5-r9 schedule family exhausted at ~33% MfmaUtil:
// 128x64/wave has FLOP/LDS-byte=85 < the 89 B/cy the MX pipe demands ->
// LDS-read co-critical under every schedule):
//   4 waves (2x2), per-wave tile 128x128 -> FLOP/LDS-byte = 128; per K-tile
//   LDS reads 128KiB (~1540cy) << MFMA 2212cy.  acc = 256 f32/lane; legal
//   via __launch_bounds__(256,1) -> 512-reg unified budget (1 wave/SIMD):
//   acc 256 + af 64 + bf ping-pong 32 + addr ~40 < 512.  (r8's spill was
//   launch_bounds(512) capping at 256 regs.)  One wave/SIMD sustains the
//   matrix pipe: needs 1 MFMA ready per ~34.5cy; bf read-ahead covers.
//
// Dbuf 2x64KiB, 2-tile-deep prefetch, counted vmcnt(16), 2 barriers/tile:
//   prologue STAGE(0),STAGE(1) (16 instr each);
//   t: vmcnt(16) [drains stage(t), leaves stage(t+1)] ; barrier ;
//      compute(t) ; barrier ; STAGE(t+2) [overwrites buf t&1, read-complete]
// Chunk swizzle per 128B row: phys=(c+row)&7; linear gload_lds dest, inverse
// on global src, same perm on reads (2-way residual; af/bf rows == r15 mod 8).
// Epilogue: [64][256] f32 slab, 4 passes, 1KiB dwordx4 row stores.
// ---------------------------------------------------------------------------
#define BM 256
#define BN 256
#define BKB 128
#define NKT (KDIM / BKB)   // 16

__device__ __forceinline__ void gload_lds16(const uint8_t* g, uint8_t* l) {
    __builtin_amdgcn_global_load_lds(
        (const __attribute__((address_space(1))) void*)g,
        (__attribute__((address_space(3))) void*)l, 16, 0, 0);
}

__device__ __forceinline__ void barrier_raw() {
    asm volatile("" ::: "memory");
    __builtin_amdgcn_s_barrier();
    asm volatile("" ::: "memory");
}

__global__ __launch_bounds__(256, 1) void gemm_fp8_kernel(
    const uint8_t* __restrict__ Aq, const uint8_t* __restrict__ Bq,
    const float* __restrict__ bias, const float* __restrict__ s_in,
    const float* __restrict__ s_w, float* __restrict__ out) {

    extern __shared__ uint8_t lds[];   // 131072 B: 2 x 64KiB kt-buffers

    // XCD-aware bijective swizzle (nwg = 512, divisible by 8)
    int nwg = gridDim.x;
    int cpx = nwg >> 3;
    int bid = blockIdx.x;
    int swz = (bid & 7) * cpx + (bid >> 3);
    int tm = swz >> 3;                 // tiles_n = 8
    int tn = swz & 7;
    int row0 = tm * BM;
    int col0 = tn * BN;

    int tid  = threadIdx.x;
    int lane = tid & 63;
    int wid  = tid >> 6;               // 4 waves
    int wr = wid >> 1, wc = wid & 1;   // 2M x 2N, each 128x128
    int r15 = lane & 15;
    int g   = lane >> 4;

    // fragment-read swizzle offsets (bytes within a row's 8 chunks)
    int perm0 = ((2 * g + r15) & 7) << 4;
    int perm1 = ((2 * g + 1 + r15) & 7) << 4;

    // ---- staging coords: per matrix 2048 chunks (256 rows x 8), 8/thread --
    int stoff[8], sdst[8];
#pragma unroll
    for (int j = 0; j < 8; ++j) {
        int p = j * 256 + tid;
        int row = p >> 3;
        int c = ((p & 7) - (row & 7)) & 7;
        stoff[j] = row * KDIM + c * 16;
        sdst[j]  = p * 16;
    }
    const uint8_t* Asrc = Aq + (size_t)row0 * KDIM;
    const uint8_t* Bsrc = Bq + (size_t)col0 * KDIM;

#define STAGE(KT)                                                             \
    {                                                                         \
        uint8_t* dst_ = &lds[((unsigned)(KT) & 1) << 16];                     \
        _Pragma("unroll")                                                     \
        for (int j_ = 0; j_ < 8; ++j_)                                        \
            gload_lds16(Asrc + stoff[j_] + (size_t)(KT) * BKB, dst_ + sdst[j_]); \
        _Pragma("unroll")                                                     \
        for (int j_ = 0; j_ < 8; ++j_)                                        \
            gload_lds16(Bsrc + stoff[j_] + (size_t)(KT) * BKB,                \
                        dst_ + 32768 + sdst[j_]);                             \
    }

    f32x4 acc[8][8];
#pragma unroll
    for (int m = 0; m < 8; ++m)
#pragma unroll
        for (int n = 0; n < 8; ++n)
            acc[m][n] = (f32x4){0.f, 0.f, 0.f, 0.f};

    i32x8 af[8], bf0, bf1;
    int aRow0 = wr * 128 + r15;        // + m*16
    int bRow0 = wc * 128 + r15;        // + n*16

#define LOAD_AF(bo)                                                           \
    _Pragma("unroll")                                                         \
    for (int m_ = 0; m_ < 8; ++m_) {                                          \
        const uint8_t* rp = lds + (bo) + (aRow0 + m_ * 16) * 128;             \
        i32x4 lo = *(const i32x4*)(rp + perm0);                               \
        i32x4 hi = *(const i32x4*)(rp + perm1);                               \
        _Pragma("unroll")                                                     \
        for (int q_ = 0; q_ < 4; ++q_) { af[m_][q_] = lo[q_]; af[m_][4 + q_] = hi[q_]; } \
    }

#define LDBF(DST, bo, N)                                                      \
    {                                                                         \
        const uint8_t* rp = lds + (bo) + 32768 + (bRow0 + (N) * 16) * 128;    \
        i32x4 lo = *(const i32x4*)(rp + perm0);                               \
        i32x4 hi = *(const i32x4*)(rp + perm1);                               \
        _Pragma("unroll")                                                     \
        for (int q_ = 0; q_ < 4; ++q_) { DST[q_] = lo[q_]; DST[4 + q_] = hi[q_]; } \
    }

#define MFMA_COL(BF, N)                                                       \
    __builtin_amdgcn_s_setprio(1);                                            \
    _Pragma("unroll")                                                         \
    for (int m_ = 0; m_ < 8; ++m_)                                            \
        acc[m_][N] = __builtin_amdgcn_mfma_scale_f32_16x16x128_f8f6f4(        \
            af[m_], BF, acc[m_][N], 0, 0, 0, 127, 0, 127);                    \
    __builtin_amdgcn_s_setprio(0);

    // ---- prologue: stage tiles 0 and 1 (16 instr each, 32 in flight) ----
    STAGE(0);
    STAGE(1);

    for (int t = 0; t < NKT; ++t) {
        if (t + 1 < NKT) asm volatile("s_waitcnt vmcnt(16)" ::: "memory");
        else             asm volatile("s_waitcnt vmcnt(0)" ::: "memory");
        barrier_raw();
        const unsigned bo = (unsigned)(t & 1) << 16;
        LOAD_AF(bo);
        LDBF(bf0, bo, 0);
        LDBF(bf1, bo, 1); MFMA_COL(bf0, 0);
        LDBF(bf0, bo, 2); MFMA_COL(bf1, 1);
        LDBF(bf1, bo, 3); MFMA_COL(bf0, 2);
        LDBF(bf0, bo, 4); MFMA_COL(bf1, 3);
        LDBF(bf1, bo, 5); MFMA_COL(bf0, 4);
        LDBF(bf0, bo, 6); MFMA_COL(bf1, 5);
        LDBF(bf1, bo, 7); MFMA_COL(bf0, 6);
                          MFMA_COL(bf1, 7);
        barrier_raw();
        if (t + 2 < NKT) STAGE(t + 2);
    }

    // ---- epilogue: f16 double-round + bias; [64][256] f32 slab, 4 passes --
    float s = s_in[0] * s_w[0];
    float* slab = (float*)lds;
    __half hb[8];
#pragma unroll
    for (int n = 0; n < 8; ++n)
        hb[n] = __float2half(bias[col0 + wc * 128 + n * 16 + r15]);

#pragma unroll
    for (int q = 0; q < 4; ++q) {        // out rows [q*64, q*64+64)
        if (wr == (q >> 1)) {
            const int mh = q & 1;        // m-frags [mh*4, mh*4+4)
#pragma unroll
            for (int n = 0; n < 8; ++n) {
                int colb = wc * 128 + n * 16 + r15;
#pragma unroll
                for (int m = 0; m < 4; ++m) {
                    int sr = m * 16 + g * 4;
#pragma unroll
                    for (int r = 0; r < 4; ++r) {
                        __half h = __float2half(acc[mh * 4 + m][n][r] * s);
                        slab[(sr + r) * 256 + colb] =
                            __half2float(__hadd(h, hb[n]));
                    }
                }
            }
        }
        barrier_raw();
#pragma unroll
        for (int it = 0; it < 16; ++it) {
            int srow = wid * 16 + it;
            f32x4 vv = *(const f32x4*)&slab[srow * 256 + lane * 4];
            int grow = row0 + q * 64 + srow;
            *(f32x4*)&out[(size_t)grow * NDIM + col0 + lane * 4] = vv;
        }
        barrier_raw();
    }
#undef STAGE
#undef LOAD_AF
#undef LDBF
#undef MFMA_COL
}

// ---------------------------------------------------------------------------
extern "C" void kernel_launch(void* const* d_in, const int* in_sizes, int n_in,
                              void* d_out, int out_size, void* d_ws, size_t ws_size,
                              hipStream_t stream) {
    const float* x      = (const float*)d_in[0];   // [16384, 2048]
    const float* weight = (const float*)d_in[1];   // [2048, 2048]
    const float* bias   = (const float*)d_in[2];   // [2048]
    const float* s_in   = (const float*)d_in[3];   // [1]
    const float* s_w    = (const float*)d_in[4];   // [1]
    float* out          = (float*)d_out;

    uint8_t* xq = (uint8_t*)d_ws;                          // 33.5 MB
    uint8_t* wq = (uint8_t*)d_ws + (size_t)MDIM * KDIM;    // 4.2 MB

    quant_both_kernel<<<2304, 256, 0, stream>>>(x, xq, weight, wq, s_in, s_w);

    dim3 grid((MDIM / BM) * (NDIM / BN));   // 64 * 8 = 512
    gemm_fp8_kernel<<<grid, 256, 131072, stream>>>(xq, wq, bias, s_in, s_w, out);
}